// Round 3
// baseline (462.199 us; speedup 1.0000x reference)
//
#include <hip/hip_runtime.h>

#define LL 32
#define HH 64
#define HALF 32

typedef __attribute__((ext_vector_type(4))) float f32x4;

template <int CTRL>
__device__ __forceinline__ float dpp_add_step(float x) {
  int y = __builtin_amdgcn_update_dpp(0, __builtin_bit_cast(int, x), CTRL, 0xf, 0xf, true);
  return x + __builtin_bit_cast(float, y);
}

// 64-lane sum -> uniform value (via readlane 63).
__device__ __forceinline__ float wave_sum64(float x) {
  x = dpp_add_step<0x111>(x);  // row_shr:1
  x = dpp_add_step<0x112>(x);  // row_shr:2
  x = dpp_add_step<0x114>(x);  // row_shr:4
  x = dpp_add_step<0x118>(x);  // row_shr:8
  x = dpp_add_step<0x142>(x);  // row_bcast15
  x = dpp_add_step<0x143>(x);  // row_bcast31
  return __builtin_bit_cast(float, __builtin_amdgcn_readlane(__builtin_bit_cast(int, x), 63));
}

// Cross-half combine: every lane gets x[low32 twin] + x[high32 twin]. The
// result is identical for twin lanes (float add is commutative), so both
// halves agree bit-exactly. VALU-pipe only.
__device__ __forceinline__ float half_swap_add(float x) {
#if __has_builtin(__builtin_amdgcn_permlane32_swap)
  // With both operands = x, {pr[0][lane], pr[1][lane]} = {x[lane], x[twin]}.
  auto pr = __builtin_amdgcn_permlane32_swap(
      __builtin_bit_cast(unsigned, x), __builtin_bit_cast(unsigned, x), false, false);
  return __builtin_bit_cast(float, (unsigned)pr[0]) +
         __builtin_bit_cast(float, (unsigned)pr[1]);
#else
  return x + __shfl_xor(x, 32, 64);  // fallback: ds_bpermute path
#endif
}

// Per-lane weights: this lane's output column j, K-half rows ibase..ibase+31.
#define DECL_W(n) float w_##n = Wc[(ibase + n) * HH + j];

#define LOADG(n) f32x4 g##n = hv4[n];

// Pin all 8 staged hv groups live -> the 8 ds_read_b128 pipeline at LDS
// throughput instead of serializing on first consumption (R8 lesson).
#define PIN_ALL_G                                                             \
  asm volatile(""                                                             \
               : "+v"(g0), "+v"(g1), "+v"(g2), "+v"(g3), "+v"(g4), "+v"(g5),  \
                 "+v"(g6), "+v"(g7));

#define MV4(n, i0, i1, i2, i3)        \
  a0 = fmaf(g##n[0], w_##i0, a0);     \
  a1 = fmaf(g##n[1], w_##i1, a1);     \
  a2 = fmaf(g##n[2], w_##i2, a2);     \
  a3 = fmaf(g##n[3], w_##i3, a3);

// In-loop weight pin (R8/R10 lesson: without per-iteration liveness pressure
// the allocator re-shrinks the register file and reads serialize).
#define PIN_ALL_W                                                              \
  asm volatile(""                                                              \
               : "+v"(w_0), "+v"(w_1), "+v"(w_2), "+v"(w_3), "+v"(w_4),       \
                 "+v"(w_5), "+v"(w_6), "+v"(w_7), "+v"(w_8), "+v"(w_9),       \
                 "+v"(w_10), "+v"(w_11), "+v"(w_12), "+v"(w_13), "+v"(w_14),  \
                 "+v"(w_15), "+v"(w_16), "+v"(w_17), "+v"(w_18), "+v"(w_19),  \
                 "+v"(w_20), "+v"(w_21), "+v"(w_22), "+v"(w_23), "+v"(w_24),  \
                 "+v"(w_25), "+v"(w_26), "+v"(w_27), "+v"(w_28), "+v"(w_29),  \
                 "+v"(w_30), "+v"(w_31), "+v"(win0), "+v"(win1), "+v"(bcj),   \
                 "+v"(dwq));

// 2 waves per sample: W0 owns outputs j in [0,32), W1 owns [32,64). Within a
// wave, lane l computes output j=(l&31) over K-half i in [32*(l>>5), +32);
// halves combined via permlane32_swap. 1024 WGs x 2 waves = 2048 waves =
// 2 waves/SIMD (co-resident waves are different samples -> stalls overlap).
__global__ __launch_bounds__(128, 2) void rnn2d_kernel(
    const int* __restrict__ x, const float* __restrict__ Win,
    const float* __restrict__ Wc, const float* __restrict__ bc,
    const float* __restrict__ Wout, const float* __restrict__ bout,
    float* __restrict__ out) {
  const int tid = threadIdx.x;
  const int lane = tid & 63;
  const int wv = tid >> 6;           // wave id: output-half owner
  const int jloc = lane & 31;
  const int j = jloc + (wv << 5);    // this lane's output column
  const int half = lane >> 5;        // this lane's K-half
  const int ibase = half << 5;
  const int b = blockIdx.x;

  __shared__ float vrow[LL * HH];             // vertical carry [column][hidden]
  __shared__ __align__(16) float hvbuf[2 * HH];  // double-buffered hv (parity)
  __shared__ float dzx[2 * LL];               // row-epilogue half-dz exchange
  __shared__ int xs[LL * LL];                 // staged spins (no vmem in loop)

  DECL_W(0)  DECL_W(1)  DECL_W(2)  DECL_W(3)  DECL_W(4)  DECL_W(5)  DECL_W(6)  DECL_W(7)
  DECL_W(8)  DECL_W(9)  DECL_W(10) DECL_W(11) DECL_W(12) DECL_W(13) DECL_W(14) DECL_W(15)
  DECL_W(16) DECL_W(17) DECL_W(18) DECL_W(19) DECL_W(20) DECL_W(21) DECL_W(22) DECL_W(23)
  DECL_W(24) DECL_W(25) DECL_W(26) DECL_W(27) DECL_W(28) DECL_W(29) DECL_W(30) DECL_W(31)

  float win0 = Win[j];
  float win1 = Win[HH + j];
  float bcj = bc[j];
  // 0.5 factor folded in: wave_sum64 over DUPLICATED halves counts each j
  // twice; 0.5*dw is an exact exponent shift.
  float dwq = 0.5f * (Wout[j * 2 + 1] - Wout[j * 2 + 0]);
  const float dbout = bout[1] - bout[0];

  // Stage spins to LDS: the per-step __syncthreads would otherwise drain
  // vmcnt on in-loop global prefetches.
  const int* xb = x + b * (LL * LL);
  for (int t = tid; t < LL * LL; t += 128) xs[t] = xb[t];
  for (int t = tid; t < LL * HH; t += 128) vrow[t] = 0.f;
  hvbuf[tid] = 0.f;  // 128 floats == both parity buffers
  __syncthreads();

  unsigned prevmask = 0u;  // previous row's spins (bit c = spin at col c)
  float total_vec = 0.f;   // per-lane partial of sum(logp), wave 0 only
  float dzbuf = 0.f;       // lane k holds step-k signed half-logit-gap

#pragma unroll 1
  for (int r = 0; r < LL; ++r) {
    const int spv = (lane < LL) ? xs[r * LL + lane] : 0;
    const unsigned curmask =
        (unsigned)(__ballot(lane < LL && spv) & 0xffffffffull);

    const int odd = r & 1;
    const int d = odd ? -1 : 1;  // boustrophedon direction
    int c = odd ? (LL - 1) : 0;  // spatial column of scan step 0

#pragma unroll 2
    for (int k = 0; k < LL; ++k) {
      PIN_ALL_W

      // This lane reads only its K-half of hv (2 uniform addrs/wave -> free
      // 2-way broadcast).
      const f32x4* hv4 =
          (const f32x4*)(hvbuf + ((k & 1) ? HH : 0) + ibase);

      // Prefetch next step's vertical carry for THIS lane's output column
      // (written by this same wave last row; lane pairs share addr -> bcast).
      const int cn = (c + d) & (LL - 1);
      const float vjn = vrow[cn * HH + j];

      LOADG(0) LOADG(1) LOADG(2) LOADG(3) LOADG(4) LOADG(5) LOADG(6) LOADG(7)
      PIN_ALL_G

      // Half-dot: 32 FMAs, 4 independent chains of 8.
      float a0 = 0.f, a1 = 0.f, a2 = 0.f, a3 = 0.f;
      MV4(0, 0, 1, 2, 3)      MV4(1, 4, 5, 6, 7)
      MV4(2, 8, 9, 10, 11)    MV4(3, 12, 13, 14, 15)
      MV4(4, 16, 17, 18, 19)  MV4(5, 20, 21, 22, 23)
      MV4(6, 24, 25, 26, 27)  MV4(7, 28, 29, 30, 31)

      // newR @ Win: one-hot selects (spins are wave-uniform mask bits).
      float winc = 0.f;
      if (k > 0) {
        const unsigned sh = (curmask >> ((c - d) & 31)) & 1u;
        winc += sh ? win1 : win0;
      }
      if (r > 0) {
        const unsigned sv = (prevmask >> c) & 1u;
        winc += sv ? win1 : win0;
      }

      const float part = (a0 + a1) + (a2 + a3);
      const float pre = half_swap_add(part) + bcj + winc;  // full 64-deep dot
      const float hnew = pre > 0.f ? pre : (__expf(pre) - 1.f);  // elu

      // hv for next step; at k==31 next step is next row's step 0 (same
      // column, zero horizontal carry, cV == hnew itself).
      const float hvn = hnew + ((k < LL - 1) ? vjn : 0.f);
      if (lane < HALF) {            // one writer per output column
        vrow[c * HH + j] = hnew;    // vertical carry for next row (wave-local)
        hvbuf[((k & 1) ? 0 : HH) + j] = hvn;
      }

      // Deferred logp: this wave's half of the logit gap, signed by spin.
      // (sign distributes over the half-sum; dbout added in wave 0's half)
      const float dzh = wave_sum64(hnew * dwq) + (wv == 0 ? dbout : 0.f);
      const unsigned spin = (curmask >> c) & 1u;
      const float tv = __builtin_bit_cast(
          float, __builtin_bit_cast(unsigned, dzh) ^ (spin << 31));
      dzbuf = (lane == k) ? tv : dzbuf;

      __syncthreads();  // hv halves from both waves visible for next step
      c = cn;
    }
    prevmask = curmask;

    // Row epilogue: exchange half-gaps, softplus all 32 steps at once.
    if (lane < LL) dzx[wv * LL + lane] = dzbuf;
    __syncthreads();
    if (wv == 0) {
      const int li = lane & 31;
      const float tt = dzx[li] + dzx[LL + li];
      float lpv = -(fmaxf(tt, 0.f) + __logf(1.f + __expf(-fabsf(tt))));
      lpv = (lpv == lpv) ? lpv : -35.0f;  // nan_to_num(nan=-35)
      total_vec += (lane < LL) ? lpv : 0.f;
    }
    // (no barrier needed here: W1's next write to dzx is gated behind 32
    // per-step barriers that W0 must also reach)
  }

  if (wv == 0) {
    const float grand = wave_sum64(total_vec);
    if (lane == 0) out[b] = 0.5f * grand;  // LOGP_FACTOR * sum
  }
}

extern "C" void kernel_launch(void* const* d_in, const int* in_sizes, int n_in,
                              void* d_out, int out_size, void* d_ws, size_t ws_size,
                              hipStream_t stream) {
  const int* x = (const int*)d_in[0];
  const float* Win = (const float*)d_in[1];
  const float* Wc = (const float*)d_in[2];
  const float* bc = (const float*)d_in[3];
  const float* Wout = (const float*)d_in[4];
  const float* bout = (const float*)d_in[5];
  float* out = (float*)d_out;
  rnn2d_kernel<<<dim3(out_size), dim3(128), 0, stream>>>(x, Win, Wc, bc, Wout, bout, out);
}

// Round 5
// 363.667 us; speedup vs baseline: 1.2709x; 1.2709x over previous
//
#include <hip/hip_runtime.h>

#define LL 32
#define HH 64

template <int CTRL>
__device__ __forceinline__ float dpp_add_step(float x) {
  int y = __builtin_amdgcn_update_dpp(0, __builtin_bit_cast(int, x), CTRL, 0xf, 0xf, true);
  return x + __builtin_bit_cast(float, y);
}

// 64-lane sum -> uniform value (via readlane 63).
__device__ __forceinline__ float wave_sum64(float x) {
  x = dpp_add_step<0x111>(x);  // row_shr:1
  x = dpp_add_step<0x112>(x);  // row_shr:2
  x = dpp_add_step<0x114>(x);  // row_shr:4
  x = dpp_add_step<0x118>(x);  // row_shr:8
  x = dpp_add_step<0x142>(x);  // row_bcast15
  x = dpp_add_step<0x143>(x);  // row_bcast31
  return __builtin_bit_cast(float, __builtin_amdgcn_readlane(__builtin_bit_cast(int, x), 63));
}

// Wave-uniform broadcast of lane l's value — the LDS-free hv transport.
// readlane ignores EXEC; lane index is a compile-time constant.
__device__ __forceinline__ float rlbc(float v, int l) {
  return __builtin_bit_cast(float, __builtin_amdgcn_readlane(__builtin_bit_cast(int, v), l));
}

#define DECL_W(n) float w_##n = Wc[n * HH + lane];

// Dot-product slice: same accumulator assignment (a_{i%4} += hv[i]*w_i) and
// same i order as the 392-µs LDS baseline -> bit-identical results. The hv
// broadcast now comes from v_readlane (register), not ds_read_b128 (LDS):
// removes the per-step ds_write -> lgkmcnt -> 16x ds_read turnaround (~240 cyc
// that a lone wave/SIMD cannot hide). R3 showed 2-wave TLP loses (462 µs,
// barrier tax); this attacks the same stall with ILP instead.
#define MV4(i0, i1, i2, i3)                  \
  a0 = fmaf(rlbc(hv, i0), w_##i0, a0);       \
  a1 = fmaf(rlbc(hv, i1), w_##i1, a1);       \
  a2 = fmaf(rlbc(hv, i2), w_##i2, a2);       \
  a3 = fmaf(rlbc(hv, i3), w_##i3, a3);

// In-loop weight pin (R8/R10 lesson: without per-iteration liveness pressure
// the allocator re-shrinks the register file and loads serialize).
#define PIN_ALL_W                                                              \
  asm volatile(""                                                              \
               : "+v"(w_0), "+v"(w_1), "+v"(w_2), "+v"(w_3), "+v"(w_4),       \
                 "+v"(w_5), "+v"(w_6), "+v"(w_7), "+v"(w_8), "+v"(w_9),       \
                 "+v"(w_10), "+v"(w_11), "+v"(w_12), "+v"(w_13), "+v"(w_14),  \
                 "+v"(w_15), "+v"(w_16), "+v"(w_17), "+v"(w_18), "+v"(w_19),  \
                 "+v"(w_20), "+v"(w_21), "+v"(w_22), "+v"(w_23), "+v"(w_24),  \
                 "+v"(w_25), "+v"(w_26), "+v"(w_27), "+v"(w_28), "+v"(w_29),  \
                 "+v"(w_30), "+v"(w_31), "+v"(w_32), "+v"(w_33), "+v"(w_34),  \
                 "+v"(w_35), "+v"(w_36), "+v"(w_37), "+v"(w_38), "+v"(w_39),  \
                 "+v"(w_40), "+v"(w_41), "+v"(w_42), "+v"(w_43), "+v"(w_44),  \
                 "+v"(w_45), "+v"(w_46), "+v"(w_47), "+v"(w_48), "+v"(w_49),  \
                 "+v"(w_50), "+v"(w_51), "+v"(w_52), "+v"(w_53), "+v"(w_54),  \
                 "+v"(w_55), "+v"(w_56), "+v"(w_57), "+v"(w_58), "+v"(w_59),  \
                 "+v"(w_60), "+v"(w_61), "+v"(w_62), "+v"(w_63), "+v"(win0),  \
                 "+v"(win1), "+v"(bcj), "+v"(dwout));

// One wave per sample, 1024 blocks = 1 wave/SIMD on all 1024 SIMDs (R7: with
// exactly B=1024 waves, concentrating waves trades SIMD count 1:1; R3 this
// session: 2-wave split = 462 µs, barrier+tail tax > halved-dot gain).
__global__ __launch_bounds__(64, 1) void rnn2d_kernel(
    const int* __restrict__ x, const float* __restrict__ Win,
    const float* __restrict__ Wc, const float* __restrict__ bc,
    const float* __restrict__ Wout, const float* __restrict__ bout,
    float* __restrict__ out) {
  const int lane = threadIdx.x;
  const int b = blockIdx.x;
  __shared__ float vrow[LL * HH];  // vertical carry [column][hidden]

  DECL_W(0)  DECL_W(1)  DECL_W(2)  DECL_W(3)  DECL_W(4)  DECL_W(5)  DECL_W(6)  DECL_W(7)
  DECL_W(8)  DECL_W(9)  DECL_W(10) DECL_W(11) DECL_W(12) DECL_W(13) DECL_W(14) DECL_W(15)
  DECL_W(16) DECL_W(17) DECL_W(18) DECL_W(19) DECL_W(20) DECL_W(21) DECL_W(22) DECL_W(23)
  DECL_W(24) DECL_W(25) DECL_W(26) DECL_W(27) DECL_W(28) DECL_W(29) DECL_W(30) DECL_W(31)
  DECL_W(32) DECL_W(33) DECL_W(34) DECL_W(35) DECL_W(36) DECL_W(37) DECL_W(38) DECL_W(39)
  DECL_W(40) DECL_W(41) DECL_W(42) DECL_W(43) DECL_W(44) DECL_W(45) DECL_W(46) DECL_W(47)
  DECL_W(48) DECL_W(49) DECL_W(50) DECL_W(51) DECL_W(52) DECL_W(53) DECL_W(54) DECL_W(55)
  DECL_W(56) DECL_W(57) DECL_W(58) DECL_W(59) DECL_W(60) DECL_W(61) DECL_W(62) DECL_W(63)

  float win0 = Win[lane];
  float win1 = Win[HH + lane];
  float bcj = bc[lane];
  float dwout = Wout[lane * 2 + 1] - Wout[lane * 2 + 0];
  const float dbout = bout[1] - bout[0];

  // Row 0 sees zero vertical hidden carry; step-0 hv is also zero.
#pragma unroll
  for (int c0 = 0; c0 < LL; ++c0) vrow[c0 * HH + lane] = 0.f;

  const int* xb = x + b * (LL * LL);
  unsigned prevmask = 0u;                // previous row's spins (bit c = spin at col c)
  int spv = (lane < LL) ? xb[lane] : 0;  // prefetched row-0 spins
  float total_vec = 0.f;                 // per-lane partial of sum(logp)
  float dzbuf = 0.f;                     // lane k holds step-k signed logit gap
  float hv = 0.f;                        // lane j's hv[j]: register-resident recurrence

#pragma unroll 1
  for (int r = 0; r < LL; ++r) {
    const unsigned curmask =
        (unsigned)(__ballot(lane < LL && spv) & 0xffffffffull);
    if (r < LL - 1) spv = (lane < LL) ? xb[(r + 1) * LL + lane] : 0;

    const int odd = r & 1;
    const int d = odd ? -1 : 1;       // boustrophedon direction
    int c = odd ? (LL - 1) : 0;       // spatial column of scan step 0

#pragma unroll 2
    for (int k = 0; k < LL; ++k) {
      PIN_ALL_W

      // Prefetch next step's vertical carry (lane-strided, conflict-free;
      // that column is not yet overwritten this row; off the serial chain).
      const int cn = (c + d) & (LL - 1);
      const float vjn = vrow[cn * HH + lane];

      // newH[j] = sum_i hv[i]*Wc[i][j]: 64 readlane-broadcasts feeding 64
      // FMAs in 4 independent chains. No LDS on the recurrence path.
      float a0 = 0.f, a1 = 0.f, a2 = 0.f, a3 = 0.f;
      MV4(0, 1, 2, 3)      MV4(4, 5, 6, 7)      MV4(8, 9, 10, 11)
      MV4(12, 13, 14, 15)  MV4(16, 17, 18, 19)  MV4(20, 21, 22, 23)
      MV4(24, 25, 26, 27)  MV4(28, 29, 30, 31)  MV4(32, 33, 34, 35)
      MV4(36, 37, 38, 39)  MV4(40, 41, 42, 43)  MV4(44, 45, 46, 47)
      MV4(48, 49, 50, 51)  MV4(52, 53, 54, 55)  MV4(56, 57, 58, 59)
      MV4(60, 61, 62, 63)

      // newR @ Win: one-hot selects (spins are wave-uniform bits of the masks).
      float winc = 0.f;
      if (k > 0) {
        const unsigned sh = (curmask >> ((c - d) & 31)) & 1u;
        winc += sh ? win1 : win0;
      }
      if (r > 0) {
        const unsigned sv = (prevmask >> c) & 1u;
        winc += sv ? win1 : win0;
      }

      const float pre = ((a0 + a1) + (a2 + a3)) + bcj + winc;
      const float hnew = pre > 0.f ? pre : (__expf(pre) - 1.f);  // elu

      vrow[c * HH + lane] = hnew;  // vertical carry for next row (off-chain)

      // hv for next step stays in-register. At k==31 the next step is the
      // next row's step 0: same column, zero horizontal carry.
      hv = hnew + ((k < LL - 1) ? vjn : 0.f);

      // Deferred logp: stash signed logit gap t_k in lane k; softplus once/row.
      const float dzv = wave_sum64(hnew * dwout) + dbout;  // z1 - z0, uniform
      const unsigned spin = (curmask >> c) & 1u;
      const float tv = __builtin_bit_cast(
          float, __builtin_bit_cast(unsigned, dzv) ^ (spin << 31));
      dzbuf = (lane == k) ? tv : dzbuf;

      c = cn;
    }
    prevmask = curmask;

    // Row epilogue: softplus for all 32 steps at once (lanes 0..31 hold t_k).
    const float tt = dzbuf;
    float lpv = -(fmaxf(tt, 0.f) + __logf(1.f + __expf(-fabsf(tt))));
    lpv = (lpv == lpv) ? lpv : -35.0f;  // nan_to_num(nan=-35)
    total_vec += (lane < LL) ? lpv : 0.f;
  }

  const float grand = wave_sum64(total_vec);
  if (lane == 0) out[b] = 0.5f * grand;  // LOGP_FACTOR * sum
}

extern "C" void kernel_launch(void* const* d_in, const int* in_sizes, int n_in,
                              void* d_out, int out_size, void* d_ws, size_t ws_size,
                              hipStream_t stream) {
  const int* x = (const int*)d_in[0];
  const float* Win = (const float*)d_in[1];
  const float* Wc = (const float*)d_in[2];
  const float* bc = (const float*)d_in[3];
  const float* Wout = (const float*)d_in[4];
  const float* bout = (const float*)d_in[5];
  float* out = (float*)d_out;
  rnn2d_kernel<<<dim3(out_size), dim3(64), 0, stream>>>(x, Win, Wc, bc, Wout, bout, out);
}